// Round 4
// baseline (205.719 us; speedup 1.0000x reference)
//
#include <hip/hip_runtime.h>

typedef __bf16 bf16;
typedef bf16  bf16x8 __attribute__((ext_vector_type(8)));
typedef bf16  bf16x4 __attribute__((ext_vector_type(4)));
typedef float f32x4  __attribute__((ext_vector_type(4)));

#define MFMA16(a, b, c) __builtin_amdgcn_mfma_f32_16x16x32_bf16((a), (b), (c), 0, 0, 0)
#define AS1 __attribute__((address_space(1)))
#define AS3 __attribute__((address_space(3)))

// async global->LDS, 16B per lane; LDS dest = (wave-uniform) base + lane*16
__device__ __forceinline__ void gld_lds16(const bf16* g, bf16* l) {
    __builtin_amdgcn_global_load_lds((AS1 void*)(g), (AS3 void*)(l), 16, 0, 0);
}

// XOR swizzle: all LDS tiles are [rows][32 elems] (64B rows, 4 chunks of 16B).
// Logical chunk c of row r lives at physical chunk c ^ ((r>>1)&3).
//  - fragment reads (row = 16*base + lr, logical chunk g): physical chunk = g ^ ((lr>>1)&3)
//    -> 8 bank-groups x 2 lanes = 2/bank = conflict-free (m136).
//  - staging: permute the GLOBAL source instead: logical chunk = (lane&3) ^ ((lane>>3)&3).

// ---------------- fused fp32 -> bf16 casts (x + 4 weights, one dispatch) ----------------
__global__ __launch_bounds__(256) void cvt_all(const float* __restrict__ x,
                                               const float* __restrict__ Wq, const float* __restrict__ Wk,
                                               const float* __restrict__ Wv, const float* __restrict__ Wu,
                                               bf16* ox, bf16* oq, bf16* ok, bf16* ov, bf16* ou,
                                               float sq, float sk) {
    int bid = blockIdx.x;
    const float* src; bf16* dst; float sc; int base;
    if (bid < 4096) { src = x; dst = ox; sc = 1.0f; base = bid; }
    else {
        int w = (bid - 4096) >> 10; base = (bid - 4096) & 1023;
        switch (w) {
            case 0:  src = Wq; dst = oq; sc = sq;   break;
            case 1:  src = Wk; dst = ok; sc = sk;   break;
            case 2:  src = Wv; dst = ov; sc = 1.0f; break;
            default: src = Wu; dst = ou; sc = 1.0f; break;
        }
    }
    int idx = (base * 256 + threadIdx.x) * 4;
    float4 v = *(const float4*)(src + idx);
    bf16x4 o;
    o[0] = (bf16)(v.x * sc); o[1] = (bf16)(v.y * sc);
    o[2] = (bf16)(v.z * sc); o[3] = (bf16)(v.w * sc);
    *(bf16x4*)(dst + idx) = o;
}

// ---------------- shared NT-GEMM core: C[m,n] = sum_k A[m,k]*B[n,k] ----------------
// 128x128 tile, BK=64 (k-plane-split [2][128][32]), K=1024. 256 threads = 4 waves (2x2).
// BK=64 halves barrier-drain count vs BK=32; 32KB LDS keeps 3 blocks/CU.
__device__ __forceinline__ void gemm_core(const bf16* __restrict__ A, const bf16* __restrict__ B,
                                          int mBase, int nBase,
                                          bf16 (*As)[128][32], bf16 (*Bs)[128][32],
                                          f32x4 acc[4][4]) {
    const int tid = threadIdx.x;
    const int wave = tid >> 6, lane = tid & 63;
    const int g = lane >> 4, lr = lane & 15;
    const int wm = (wave & 1) << 6, wn = (wave >> 1) << 6;
    const int q = lane >> 2;
    const int cswz = ((lane & 3) ^ ((lane >> 3) & 3)) << 3;
    const int pcs  = (g ^ ((lr >> 1) & 3)) << 3;

    // per wave 4 A-batches + 4 B-batches per iter: bi = wave*4+i; p = bi>>3, rb = (bi&7)*16
    const int bi0 = wave << 2;

    for (int k0 = 0; k0 < 1024; k0 += 64) {
        __syncthreads();
#pragma unroll
        for (int i = 0; i < 4; i++) {
            int bi = bi0 + i;
            int p = bi >> 3, rb = (bi & 7) << 4;
            int kof = k0 + (p << 5) + cswz;
            gld_lds16(A + (size_t)(mBase + rb + q) * 1024 + kof, &As[p][rb][0]);
            gld_lds16(B + (size_t)(nBase + rb + q) * 1024 + kof, &Bs[p][rb][0]);
        }
        __syncthreads();

#pragma unroll
        for (int ks = 0; ks < 2; ks++) {
            bf16x8 af[4], bfr[4];
#pragma unroll
            for (int i = 0; i < 4; i++)
                af[i] = *(const bf16x8*)&As[ks][wm + (i << 4) + lr][pcs];
#pragma unroll
            for (int j = 0; j < 4; j++)
                bfr[j] = *(const bf16x8*)&Bs[ks][wn + (j << 4) + lr][pcs];
#pragma unroll
            for (int i = 0; i < 4; i++)
#pragma unroll
                for (int j = 0; j < 4; j++)
                    acc[i][j] = MFMA16(af[i], bfr[j], acc[i][j]);
        }
    }
}

// ---------------- QKV GEMM ----------------
// z=0 -> Q[b,h,t,d], z=1 -> K[b,h,t,d]: C = x @ W^T (m=token, n=feature)
// z=2 -> V^T[b,h,d,t]: role-swapped, C = Wv @ x^T (m=feature, n=token) -> row-major C IS V^T.
__global__ __launch_bounds__(256) void gemm_qkv(const bf16* __restrict__ A,
                                                const bf16* __restrict__ Wq, const bf16* __restrict__ Wk,
                                                const bf16* __restrict__ Wv,
                                                bf16* __restrict__ Qo, bf16* __restrict__ Ko,
                                                bf16* __restrict__ Vto) {
    __shared__ bf16 As[2][128][32];
    __shared__ bf16 Bs[2][128][32];
    const int tid = threadIdx.x;
    const int wave = tid >> 6, lane = tid & 63;
    const int g = lane >> 4, lr = lane & 15;
    const int wm = (wave & 1) << 6, wn = (wave >> 1) << 6;
    const int z = blockIdx.z;

    const bf16 *Ap, *Bp;
    int mBase, nBase;
    if (z == 2) { Ap = Wv; Bp = A;            mBase = blockIdx.x * 128; nBase = blockIdx.y * 128; }
    else        { Ap = A;  Bp = z ? Wk : Wq;  mBase = blockIdx.y * 128; nBase = blockIdx.x * 128; }

    f32x4 acc[4][4] = {};
    gemm_core(Ap, Bp, mBase, nBase, As, Bs, acc);

    // C/D layout: row m = g*4+r, col n = lr (verified m89/m91)
#pragma unroll
    for (int i = 0; i < 4; i++)
#pragma unroll
        for (int j = 0; j < 4; j++)
#pragma unroll
            for (int r = 0; r < 4; r++) {
                int m = mBase + wm + (i << 4) + (g << 2) + r;
                int n = nBase + wn + (j << 4) + lr;
                bf16 v = (bf16)acc[i][j][r];
                if (z == 2) {
                    int h = m >> 6, d = m & 63, b = n >> 11, t = n & 2047;
                    Vto[((size_t)(((b << 4) + h) << 6) + d) * 2048 + t] = v;  // [b,h,d,t]
                } else {
                    int b = m >> 11, t = m & 2047, h = n >> 6, d = n & 63;
                    bf16* dst = (z == 0) ? Qo : Ko;
                    dst[(((size_t)((b << 4) + h) * 2048 + t) << 6) + d] = v;  // [b,h,t,d]
                }
            }
}

// ---------------- output GEMM: out = attn @ Wu^T + bu (fp32 out) ----------------
__global__ __launch_bounds__(256) void gemm_out(const bf16* __restrict__ A, const bf16* __restrict__ B,
                                                const float* __restrict__ bias, float* __restrict__ out) {
    __shared__ bf16 As[2][128][32];
    __shared__ bf16 Bs[2][128][32];
    const int tid = threadIdx.x;
    const int wave = tid >> 6, lane = tid & 63;
    const int g = lane >> 4, lr = lane & 15;
    const int wm = (wave & 1) << 6, wn = (wave >> 1) << 6;
    const int mBase = blockIdx.y * 128, nBase = blockIdx.x * 128;

    f32x4 acc[4][4] = {};
    gemm_core(A, B, mBase, nBase, As, Bs, acc);

#pragma unroll
    for (int i = 0; i < 4; i++)
#pragma unroll
        for (int j = 0; j < 4; j++) {
            int n = nBase + wn + (j << 4) + lr;
            float bv = bias[n];
#pragma unroll
            for (int r = 0; r < 4; r++) {
                int m = mBase + wm + (i << 4) + (g << 2) + r;
                out[((size_t)m << 10) + n] = acc[i][j][r] + bv;
            }
        }
}

// ---------------- attention ----------------
// Per block: one (b,h), 128 Q rows (4 waves x 32t). S-chunks of 128.
// S^T = K@Q^T (C rows = s-dim); P transposed via per-wave 2KB LDS plane per ks2.
// lsum via ones-MFMA: PV against an all-ones B-fragment yields row-sums with the SAME
// (g,r)->t mapping as oacc -> zero-shuffle normalization, no VALU adds in the hot loop.
// Wq pre-scaled by log2(e): softmax uses raw v_exp_f32 (exp2).
__global__ __launch_bounds__(256) void attn(const bf16* __restrict__ Q, const bf16* __restrict__ Kt,
                                            const bf16* __restrict__ Vt, bf16* __restrict__ O) {
    __shared__ bf16 Qs[2][128][32];   // 16KB [ks][t][d-half]; dead after qf extraction -> Ps alias
    __shared__ bf16 Ks[2][128][32];   // 16KB [ks][s][d-half]
    __shared__ bf16 Vs[4][64][32];    // 16KB [ks2][d][s-quarter]
    bf16 (*Ps)[32][32] = (bf16(*)[32][32]) & Qs[0][0][0];  // 8KB alias: [wave][t][s-quarter]

    const int tid = threadIdx.x;
    const int wave = tid >> 6, lane = tid & 63;
    const int g = lane >> 4, lr = lane & 15;
    const int q = lane >> 2;
    const int cswz = ((lane & 3) ^ ((lane >> 3) & 3)) << 3;
    const int pcs  = (g ^ ((lr >> 1) & 3)) << 3;
    // P-write physical offsets (b64): logical chunk isub*2+(g>>1), sub (g&1)*4
    const int pw0 = ((((g >> 1))     ^ ((lr >> 1) & 3)) << 3) + ((g & 1) << 2);
    const int pw1 = (((2 + (g >> 1)) ^ ((lr >> 1) & 3)) << 3) + ((g & 1) << 2);

    const int bh = blockIdx.y;
    const int qBase = blockIdx.x << 7;

    const bf16* Qg = Q + ((size_t)bh * 2048 + qBase) * 64;
    const bf16* Kg = Kt + (size_t)bh * 2048 * 64;
    const bf16* Vg = Vt + (size_t)bh * 64 * 2048;

    // stage Q: 16 batches of 1KB, plane-split [p][16 rows][32], swizzled source
#pragma unroll
    for (int i = 0; i < 4; i++) {
        int bi = (wave << 2) + i;
        int p = bi >> 3, rb = (bi & 7) << 4;
        gld_lds16(Qg + (rb + q) * 64 + (p << 5) + cswz, &Qs[p][rb][0]);
    }
    __syncthreads();

    bf16x8 qf[2][2];
#pragma unroll
    for (int ks = 0; ks < 2; ks++)
#pragma unroll
        for (int tt = 0; tt < 2; tt++)
            qf[ks][tt] = *(const bf16x8*)&Qs[ks][(wave << 5) + (tt << 4) + lr][pcs];

    bf16x8 ones;
#pragma unroll
    for (int i = 0; i < 8; i++) ones[i] = (bf16)1.0f;

    f32x4 oacc[2][4] = {};
    f32x4 oaccL[2] = {};   // row-sum accumulator (ones-tile)

    for (int s0 = 0; s0 < 2048; s0 += 128) {
        __syncthreads();   // drains lgkm: qf/prior-iter fragment reads done everywhere
#pragma unroll
        for (int i = 0; i < 4; i++) {
            int bi = (wave << 2) + i;
            {   // K chunk: [2][128][32]
                int p = bi >> 3, rb = (bi & 7) << 4;
                gld_lds16(Kg + (size_t)(s0 + rb + q) * 64 + (p << 5) + cswz, &Ks[p][rb][0]);
            }
            {   // V chunk: [4][64][32]
                int p = bi >> 2, rb = (bi & 3) << 4;
                gld_lds16(Vg + (size_t)(rb + q) * 2048 + s0 + (p << 5) + cswz, &Vs[p][rb][0]);
            }
        }
        __syncthreads();

#pragma unroll
        for (int ks2 = 0; ks2 < 4; ks2++) {
            // S^T for s-quarter ks2: tiles is = 2*ks2, 2*ks2+1
            f32x4 sacc[2][2] = {};
#pragma unroll
            for (int isub = 0; isub < 2; isub++) {
                int is = (ks2 << 1) + isub;
#pragma unroll
                for (int ks = 0; ks < 2; ks++) {
                    bf16x8 kf = *(const bf16x8*)&Ks[ks][(is << 4) + lr][pcs];
                    sacc[isub][0] = MFMA16(kf, qf[ks][0], sacc[isub][0]);
                    sacc[isub][1] = MFMA16(kf, qf[ks][1], sacc[isub][1]);
                }
            }
            // exp2 + pack into P plane [t][32] (swizzled b64 writes)
#pragma unroll
            for (int isub = 0; isub < 2; isub++)
#pragma unroll
                for (int tt = 0; tt < 2; tt++) {
                    f32x4 s = sacc[isub][tt];
                    bf16x4 pb;
                    pb[0] = (bf16)__builtin_amdgcn_exp2f(s[0]);
                    pb[1] = (bf16)__builtin_amdgcn_exp2f(s[1]);
                    pb[2] = (bf16)__builtin_amdgcn_exp2f(s[2]);
                    pb[3] = (bf16)__builtin_amdgcn_exp2f(s[3]);
                    *(bf16x4*)&Ps[wave][(tt << 4) + lr][isub ? pw1 : pw0] = pb;
                }
            // O += P_plane @ V_plane; L += P_plane @ ones (same-wave DS in-order)
            bf16x8 pf0 = *(const bf16x8*)&Ps[wave][lr][pcs];
            bf16x8 pf1 = *(const bf16x8*)&Ps[wave][16 + lr][pcs];
#pragma unroll
            for (int jd = 0; jd < 4; jd++) {
                bf16x8 vf = *(const bf16x8*)&Vs[ks2][(jd << 4) + lr][pcs];
                oacc[0][jd] = MFMA16(pf0, vf, oacc[0][jd]);
                oacc[1][jd] = MFMA16(pf1, vf, oacc[1][jd]);
            }
            oaccL[0] = MFMA16(pf0, ones, oaccL[0]);
            oaccL[1] = MFMA16(pf1, ones, oaccL[1]);
        }
    }

    // normalization: oaccL rows align with oacc rows (same A-fragment) -> no shuffles
    float linv[2][4];
#pragma unroll
    for (int tt = 0; tt < 2; tt++)
#pragma unroll
        for (int r = 0; r < 4; r++)
            linv[tt][r] = 1.0f / oaccL[tt][r];

    const int b = bh >> 4, h = bh & 15;
#pragma unroll
    for (int tt = 0; tt < 2; tt++)
#pragma unroll
        for (int jd = 0; jd < 4; jd++)
#pragma unroll
            for (int r = 0; r < 4; r++) {
                int t = qBase + (wave << 5) + (tt << 4) + (g << 2) + r;
                int col = (h << 6) + (jd << 4) + lr;
                O[(((size_t)(b * 2048 + t)) << 10) + col] = (bf16)(oacc[tt][jd][r] * linv[tt][r]);
            }
}

extern "C" void kernel_launch(void* const* d_in, const int* in_sizes, int n_in,
                              void* d_out, int out_size, void* d_ws, size_t ws_size,
                              hipStream_t stream) {
    const float* x  = (const float*)d_in[0];
    const float* Wq = (const float*)d_in[1];
    const float* Wk = (const float*)d_in[2];
    const float* Wv = (const float*)d_in[3];
    const float* Wu = (const float*)d_in[4];
    const float* bu = (const float*)d_in[5];
    float* out = (float*)d_out;

    char* ws = (char*)d_ws;
    bf16* xbf  = (bf16*)(ws);                      // 8MB; reused as attn output after QKV GEMM
    bf16* wqbf = (bf16*)(ws + ((size_t)8  << 20));
    bf16* wkbf = (bf16*)(ws + ((size_t)10 << 20));
    bf16* wvbf = (bf16*)(ws + ((size_t)12 << 20));
    bf16* wubf = (bf16*)(ws + ((size_t)14 << 20));
    bf16* Qb   = (bf16*)(ws + ((size_t)16 << 20)); // [b,h,t,d] 8MB
    bf16* Kb   = (bf16*)(ws + ((size_t)24 << 20)); // [b,h,t,d] 8MB
    bf16* Vtb  = (bf16*)(ws + ((size_t)32 << 20)); // [b,h,d,t] 8MB
    bf16* attnO = xbf;                             // overlay: x dead after gemm_qkv

    const float iscale_k = 0.17677669529663687f;   // 1024^-0.25
    const float iscale_q = 0.25503540109f;         // 1024^-0.25 * log2(e) -> scores in log2 domain

    cvt_all<<<8192, 256, 0, stream>>>(x, Wq, Wk, Wv, Wu, xbf, wqbf, wkbf, wvbf, wubf,
                                      iscale_q, iscale_k);

    gemm_qkv<<<dim3(8, 32, 3), 256, 0, stream>>>(xbf, wqbf, wkbf, wvbf, Qb, Kb, Vtb);
    attn<<<dim3(16, 32), 256, 0, stream>>>(Qb, Kb, Vtb, attnO);
    gemm_out<<<dim3(8, 32), 256, 0, stream>>>(attnO, wubf, bu, out);
}

// Round 5
// 193.780 us; speedup vs baseline: 1.0616x; 1.0616x over previous
//
#include <hip/hip_runtime.h>

typedef __bf16 bf16;
typedef bf16  bf16x8 __attribute__((ext_vector_type(8)));
typedef bf16  bf16x4 __attribute__((ext_vector_type(4)));
typedef float f32x4  __attribute__((ext_vector_type(4)));

#define MFMA16(a, b, c) __builtin_amdgcn_mfma_f32_16x16x32_bf16((a), (b), (c), 0, 0, 0)
#define AS1 __attribute__((address_space(1)))
#define AS3 __attribute__((address_space(3)))

// async global->LDS, 16B per lane; LDS dest = (wave-uniform) base + lane*16
__device__ __forceinline__ void gld_lds16(const bf16* g, bf16* l) {
    __builtin_amdgcn_global_load_lds((AS1 void*)(g), (AS3 void*)(l), 16, 0, 0);
}

// XOR swizzle: all LDS tiles are [rows][32 elems] (64B rows, 4 chunks of 16B).
// Logical chunk c of row r lives at physical chunk c ^ ((r>>1)&3).
//  - fragment reads (row = 16*base + lr, logical chunk g): physical chunk = g ^ ((lr>>1)&3)
//    -> 8 bank-groups x 2 lanes = 2/bank = conflict-free (m136).
//  - staging: permute the GLOBAL source instead: logical chunk = (lane&3) ^ ((lane>>3)&3).

// ---------------- fused fp32 -> bf16 casts (x + 4 weights, one dispatch) ----------------
__global__ __launch_bounds__(256) void cvt_all(const float* __restrict__ x,
                                               const float* __restrict__ Wq, const float* __restrict__ Wk,
                                               const float* __restrict__ Wv, const float* __restrict__ Wu,
                                               bf16* ox, bf16* oq, bf16* ok, bf16* ov, bf16* ou,
                                               float sq, float sk) {
    int bid = blockIdx.x;
    const float* src; bf16* dst; float sc; int base;
    if (bid < 4096) { src = x; dst = ox; sc = 1.0f; base = bid; }
    else {
        int w = (bid - 4096) >> 10; base = (bid - 4096) & 1023;
        switch (w) {
            case 0:  src = Wq; dst = oq; sc = sq;   break;
            case 1:  src = Wk; dst = ok; sc = sk;   break;
            case 2:  src = Wv; dst = ov; sc = 1.0f; break;
            default: src = Wu; dst = ou; sc = 1.0f; break;
        }
    }
    int idx = (base * 256 + threadIdx.x) * 4;
    float4 v = *(const float4*)(src + idx);
    bf16x4 o;
    o[0] = (bf16)(v.x * sc); o[1] = (bf16)(v.y * sc);
    o[2] = (bf16)(v.z * sc); o[3] = (bf16)(v.w * sc);
    *(bf16x4*)(dst + idx) = o;
}

// ---------------- shared NT-GEMM core: C[m,n] = sum_k A[m,k]*B[n,k] ----------------
// 128x128 tile, BK=32, K=1024. 256 threads = 4 waves (2x2, each 64x64 = 4x4 MFMA tiles).
// BK=32 is the measured optimum (BK=64 regressed ~8us in R4 — m132 pattern).
__device__ __forceinline__ void gemm_core(const bf16* __restrict__ A, const bf16* __restrict__ B,
                                          int mBase, int nBase, bf16* As, bf16* Bs,
                                          f32x4 acc[4][4]) {
    const int tid = threadIdx.x;
    const int wave = tid >> 6, lane = tid & 63;
    const int g = lane >> 4, lr = lane & 15;
    const int wm = (wave & 1) << 6, wn = (wave >> 1) << 6;
    const int q = lane >> 2;
    const int cswz = ((lane & 3) ^ ((lane >> 3) & 3)) << 3;   // staging source chunk (elems)
    const int pcs  = (g ^ ((lr >> 1) & 3)) << 3;              // fragment physical chunk (elems)

    const int rb0 = wave << 4, rb1 = rb0 + 64;
    const bf16* a0 = A + (size_t)(mBase + rb0 + q) * 1024 + cswz;
    const bf16* a1 = A + (size_t)(mBase + rb1 + q) * 1024 + cswz;
    const bf16* b0 = B + (size_t)(nBase + rb0 + q) * 1024 + cswz;
    const bf16* b1 = B + (size_t)(nBase + rb1 + q) * 1024 + cswz;

    for (int k0 = 0; k0 < 1024; k0 += 32) {
        __syncthreads();
        gld_lds16(a0 + k0, As + rb0 * 32);
        gld_lds16(a1 + k0, As + rb1 * 32);
        gld_lds16(b0 + k0, Bs + rb0 * 32);
        gld_lds16(b1 + k0, Bs + rb1 * 32);
        __syncthreads();

        bf16x8 af[4], bfr[4];
#pragma unroll
        for (int i = 0; i < 4; i++)
            af[i] = *(const bf16x8*)&As[(wm + (i << 4) + lr) * 32 + pcs];
#pragma unroll
        for (int j = 0; j < 4; j++)
            bfr[j] = *(const bf16x8*)&Bs[(wn + (j << 4) + lr) * 32 + pcs];
#pragma unroll
        for (int i = 0; i < 4; i++)
#pragma unroll
            for (int j = 0; j < 4; j++)
                acc[i][j] = MFMA16(af[i], bfr[j], acc[i][j]);
    }
}

// ---------------- QKV GEMM ----------------
// z=0 -> Q[b,h,t,d], z=1 -> K[b,h,t,d]: C = x @ W^T (m=token, n=feature)
// z=2 -> V^T[b,h,d,t]: role-swapped, C = Wv @ x^T (m=feature, n=token) -> row-major C IS V^T.
__global__ __launch_bounds__(256) void gemm_qkv(const bf16* __restrict__ A,
                                                const bf16* __restrict__ Wq, const bf16* __restrict__ Wk,
                                                const bf16* __restrict__ Wv,
                                                bf16* __restrict__ Qo, bf16* __restrict__ Ko,
                                                bf16* __restrict__ Vto) {
    __shared__ bf16 As[128 * 32];
    __shared__ bf16 Bs[128 * 32];
    const int tid = threadIdx.x;
    const int wave = tid >> 6, lane = tid & 63;
    const int g = lane >> 4, lr = lane & 15;
    const int wm = (wave & 1) << 6, wn = (wave >> 1) << 6;
    const int z = blockIdx.z;

    const bf16 *Ap, *Bp;
    int mBase, nBase;
    if (z == 2) { Ap = Wv; Bp = A;            mBase = blockIdx.x * 128; nBase = blockIdx.y * 128; }
    else        { Ap = A;  Bp = z ? Wk : Wq;  mBase = blockIdx.y * 128; nBase = blockIdx.x * 128; }

    f32x4 acc[4][4] = {};
    gemm_core(Ap, Bp, mBase, nBase, As, Bs, acc);

    // C/D layout: row m = g*4+r, col n = lr (verified m89/m91)
#pragma unroll
    for (int i = 0; i < 4; i++)
#pragma unroll
        for (int j = 0; j < 4; j++)
#pragma unroll
            for (int r = 0; r < 4; r++) {
                int m = mBase + wm + (i << 4) + (g << 2) + r;
                int n = nBase + wn + (j << 4) + lr;
                bf16 v = (bf16)acc[i][j][r];
                if (z == 2) {
                    int h = m >> 6, d = m & 63, b = n >> 11, t = n & 2047;
                    Vto[((size_t)(((b << 4) + h) << 6) + d) * 2048 + t] = v;  // [b,h,d,t]
                } else {
                    int b = m >> 11, t = m & 2047, h = n >> 6, d = n & 63;
                    bf16* dst = (z == 0) ? Qo : Ko;
                    dst[(((size_t)((b << 4) + h) * 2048 + t) << 6) + d] = v;  // [b,h,t,d]
                }
            }
}

// ---------------- output GEMM: out = attn @ Wu^T + bu (fp32 out) ----------------
__global__ __launch_bounds__(256) void gemm_out(const bf16* __restrict__ A, const bf16* __restrict__ B,
                                                const float* __restrict__ bias, float* __restrict__ out) {
    __shared__ bf16 As[128 * 32];
    __shared__ bf16 Bs[128 * 32];
    const int tid = threadIdx.x;
    const int wave = tid >> 6, lane = tid & 63;
    const int g = lane >> 4, lr = lane & 15;
    const int wm = (wave & 1) << 6, wn = (wave >> 1) << 6;
    const int mBase = blockIdx.y * 128, nBase = blockIdx.x * 128;

    f32x4 acc[4][4] = {};
    gemm_core(A, B, mBase, nBase, As, Bs, acc);

#pragma unroll
    for (int i = 0; i < 4; i++)
#pragma unroll
        for (int j = 0; j < 4; j++) {
            int n = nBase + wn + (j << 4) + lr;
            float bv = bias[n];
#pragma unroll
            for (int r = 0; r < 4; r++) {
                int m = mBase + wm + (i << 4) + (g << 2) + r;
                out[((size_t)m << 10) + n] = acc[i][j][r] + bv;
            }
        }
}

// ---------------- attention ----------------
// Per block: one (b,h), 64 Q rows (4 waves x 16t). 1024 blocks, 40KB LDS -> 4 blocks/CU
// (R4 showed 2 blocks/CU left ~40% both-pipes-idle latency stall).
// XCD-affinity: all 32 q-tiles of one bh share bid%8 -> per-XCD L2 holds 4 heads' K/V (2MB).
// S^T = K@Q^T (C rows = s-dim); P via per-wave 1KB LDS plane; lsum via ones-MFMA
// (row-sums land with oacc's (g,r)->t mapping -> shuffle-free normalization).
// Wq pre-scaled by log2(e): exp is raw v_exp_f32.
__global__ __launch_bounds__(256, 4) void attn(const bf16* __restrict__ Q, const bf16* __restrict__ Kt,
                                               const bf16* __restrict__ Vt, bf16* __restrict__ O) {
    __shared__ bf16 Qs[2][64][32];    // 8KB [ks][t][d-half]; dead after qf extraction -> Ps alias
    __shared__ bf16 Ks[2][128][32];   // 16KB [ks][s][d-half]
    __shared__ bf16 Vs[4][64][32];    // 16KB [ks2][d][s-quarter]
    bf16 (*Ps)[16][32] = (bf16(*)[16][32]) & Qs[0][0][0];  // 4KB alias: [wave][t][s-quarter]

    const int tid = threadIdx.x;
    const int wave = tid >> 6, lane = tid & 63;
    const int g = lane >> 4, lr = lane & 15;
    const int q = lane >> 2;
    const int cswz = ((lane & 3) ^ ((lane >> 3) & 3)) << 3;
    const int pcs  = (g ^ ((lr >> 1) & 3)) << 3;
    // P-write physical offsets (b64): logical chunk isub*2+(g>>1), sub (g&1)*4, row lr
    const int pw0 = ((((g >> 1))     ^ ((lr >> 1) & 3)) << 3) + ((g & 1) << 2);
    const int pw1 = (((2 + (g >> 1)) ^ ((lr >> 1) & 3)) << 3) + ((g & 1) << 2);

    const int bid = blockIdx.x;
    const int bh = ((bid & 7) << 2) | (bid >> 8);   // 32 q-tiles of a bh share bid%8 (XCD hint)
    const int qt = (bid >> 3) & 31;
    const int qBase = qt << 6;

    const bf16* Qg = Q + ((size_t)bh * 2048 + qBase) * 64;
    const bf16* Kg = Kt + (size_t)bh * 2048 * 64;
    const bf16* Vg = Vt + (size_t)bh * 64 * 2048;

    // stage Q: 8 batches of 1KB, 2 per wave, plane-split [p][16 rows][32], swizzled source
#pragma unroll
    for (int i = 0; i < 2; i++) {
        int bi = (wave << 1) + i;
        int p = bi >> 2, rb = (bi & 3) << 4;
        gld_lds16(Qg + (rb + q) * 64 + (p << 5) + cswz, &Qs[p][rb][0]);
    }
    __syncthreads();

    bf16x8 qf[2];
#pragma unroll
    for (int ks = 0; ks < 2; ks++)
        qf[ks] = *(const bf16x8*)&Qs[ks][(wave << 4) + lr][pcs];

    bf16x8 ones;
#pragma unroll
    for (int i = 0; i < 8; i++) ones[i] = (bf16)1.0f;

    f32x4 oacc[4] = {};
    f32x4 oaccL = {};

    for (int s0 = 0; s0 < 2048; s0 += 128) {
        __syncthreads();   // drains lgkm: qf/prior-iter fragment reads done everywhere
#pragma unroll
        for (int i = 0; i < 4; i++) {
            int bi = (wave << 2) + i;
            {   // K chunk: [2][128][32]
                int p = bi >> 3, rb = (bi & 7) << 4;
                gld_lds16(Kg + (size_t)(s0 + rb + q) * 64 + (p << 5) + cswz, &Ks[p][rb][0]);
            }
            {   // V chunk: [4][64][32]
                int p = bi >> 2, rb = (bi & 3) << 4;
                gld_lds16(Vg + (size_t)(rb + q) * 2048 + s0 + (p << 5) + cswz, &Vs[p][rb][0]);
            }
        }
        __syncthreads();

#pragma unroll
        for (int ks2 = 0; ks2 < 4; ks2++) {
            // S^T for s-quarter ks2: tiles is = 2*ks2, 2*ks2+1
            f32x4 sacc[2] = {};
#pragma unroll
            for (int isub = 0; isub < 2; isub++) {
                int is = (ks2 << 1) + isub;
#pragma unroll
                for (int ks = 0; ks < 2; ks++) {
                    bf16x8 kf = *(const bf16x8*)&Ks[ks][(is << 4) + lr][pcs];
                    sacc[isub] = MFMA16(kf, qf[ks], sacc[isub]);
                }
            }
            // exp2 + pack into P plane [t=lr][32] (swizzled b64 writes)
#pragma unroll
            for (int isub = 0; isub < 2; isub++) {
                f32x4 s = sacc[isub];
                bf16x4 pb;
                pb[0] = (bf16)__builtin_amdgcn_exp2f(s[0]);
                pb[1] = (bf16)__builtin_amdgcn_exp2f(s[1]);
                pb[2] = (bf16)__builtin_amdgcn_exp2f(s[2]);
                pb[3] = (bf16)__builtin_amdgcn_exp2f(s[3]);
                *(bf16x4*)&Ps[wave][lr][isub ? pw1 : pw0] = pb;
            }
            // O += P @ V; L += P @ ones (same-wave DS in-order: no explicit waitcnt)
            bf16x8 pf = *(const bf16x8*)&Ps[wave][lr][pcs];
#pragma unroll
            for (int jd = 0; jd < 4; jd++) {
                bf16x8 vf = *(const bf16x8*)&Vs[ks2][(jd << 4) + lr][pcs];
                oacc[jd] = MFMA16(pf, vf, oacc[jd]);
            }
            oaccL = MFMA16(pf, ones, oaccL);
        }
    }

    // normalization: oaccL rows align with oacc rows (same A-fragment) -> no shuffles
    float linv[4];
#pragma unroll
    for (int r = 0; r < 4; r++) linv[r] = 1.0f / oaccL[r];

    const int b = bh >> 4, h = bh & 15;
#pragma unroll
    for (int jd = 0; jd < 4; jd++)
#pragma unroll
        for (int r = 0; r < 4; r++) {
            int t = qBase + (wave << 4) + (g << 2) + r;
            int col = (h << 6) + (jd << 4) + lr;
            O[(((size_t)(b * 2048 + t)) << 10) + col] = (bf16)(oacc[jd][r] * linv[r]);
        }
}

extern "C" void kernel_launch(void* const* d_in, const int* in_sizes, int n_in,
                              void* d_out, int out_size, void* d_ws, size_t ws_size,
                              hipStream_t stream) {
    const float* x  = (const float*)d_in[0];
    const float* Wq = (const float*)d_in[1];
    const float* Wk = (const float*)d_in[2];
    const float* Wv = (const float*)d_in[3];
    const float* Wu = (const float*)d_in[4];
    const float* bu = (const float*)d_in[5];
    float* out = (float*)d_out;

    char* ws = (char*)d_ws;
    bf16* xbf  = (bf16*)(ws);                      // 8MB; reused as attn output after QKV GEMM
    bf16* wqbf = (bf16*)(ws + ((size_t)8  << 20));
    bf16* wkbf = (bf16*)(ws + ((size_t)10 << 20));
    bf16* wvbf = (bf16*)(ws + ((size_t)12 << 20));
    bf16* wubf = (bf16*)(ws + ((size_t)14 << 20));
    bf16* Qb   = (bf16*)(ws + ((size_t)16 << 20)); // [b,h,t,d] 8MB
    bf16* Kb   = (bf16*)(ws + ((size_t)24 << 20)); // [b,h,t,d] 8MB
    bf16* Vtb  = (bf16*)(ws + ((size_t)32 << 20)); // [b,h,d,t] 8MB
    bf16* attnO = xbf;                             // overlay: x dead after gemm_qkv

    const float iscale_k = 0.17677669529663687f;   // 1024^-0.25
    const float iscale_q = 0.25503540109f;         // 1024^-0.25 * log2(e) -> scores in log2 domain

    cvt_all<<<8192, 256, 0, stream>>>(x, Wq, Wk, Wv, Wu, xbf, wqbf, wkbf, wvbf, wubf,
                                      iscale_q, iscale_k);

    gemm_qkv<<<dim3(8, 32, 3), 256, 0, stream>>>(xbf, wqbf, wkbf, wvbf, Qb, Kb, Vtb);
    attn<<<dim3(1024), 256, 0, stream>>>(Qb, Kb, Vtb, attnO);
    gemm_out<<<dim3(8, 32), 256, 0, stream>>>(attnO, wubf, bu, out);
}

// Round 6
// 190.580 us; speedup vs baseline: 1.0794x; 1.0168x over previous
//
#include <hip/hip_runtime.h>

typedef __bf16 bf16;
typedef bf16  bf16x8 __attribute__((ext_vector_type(8)));
typedef bf16  bf16x4 __attribute__((ext_vector_type(4)));
typedef float f32x4  __attribute__((ext_vector_type(4)));

#define MFMA16(a, b, c) __builtin_amdgcn_mfma_f32_16x16x32_bf16((a), (b), (c), 0, 0, 0)
#define AS1 __attribute__((address_space(1)))
#define AS3 __attribute__((address_space(3)))

// async global->LDS, 16B per lane; LDS dest = (wave-uniform) base + lane*16
__device__ __forceinline__ void gld_lds16(const bf16* g, bf16* l) {
    __builtin_amdgcn_global_load_lds((AS1 void*)(g), (AS3 void*)(l), 16, 0, 0);
}

// XOR swizzle: all LDS tiles are [rows][32 elems] (64B rows, 4 chunks of 16B).
// Logical chunk c of row r lives at physical chunk c ^ ((r>>1)&3).
//  - fragment reads (row = 16*base + lr, logical chunk g): physical chunk = g ^ ((lr>>1)&3)
//    -> 8 bank-groups x 2 lanes = 2/bank = conflict-free (m136).
//  - staging: permute the GLOBAL source instead: logical chunk = (lane&3) ^ ((lane>>3)&3).

// ---------------- fused fp32 -> bf16 casts (x + 4 weights, one dispatch) ----------------
__global__ __launch_bounds__(256) void cvt_all(const float* __restrict__ x,
                                               const float* __restrict__ Wq, const float* __restrict__ Wk,
                                               const float* __restrict__ Wv, const float* __restrict__ Wu,
                                               bf16* ox, bf16* oq, bf16* ok, bf16* ov, bf16* ou,
                                               float sq, float sk) {
    int bid = blockIdx.x;
    const float* src; bf16* dst; float sc; int base;
    if (bid < 4096) { src = x; dst = ox; sc = 1.0f; base = bid; }
    else {
        int w = (bid - 4096) >> 10; base = (bid - 4096) & 1023;
        switch (w) {
            case 0:  src = Wq; dst = oq; sc = sq;   break;
            case 1:  src = Wk; dst = ok; sc = sk;   break;
            case 2:  src = Wv; dst = ov; sc = 1.0f; break;
            default: src = Wu; dst = ou; sc = 1.0f; break;
        }
    }
    int idx = (base * 256 + threadIdx.x) * 4;
    float4 v = *(const float4*)(src + idx);
    bf16x4 o;
    o[0] = (bf16)(v.x * sc); o[1] = (bf16)(v.y * sc);
    o[2] = (bf16)(v.z * sc); o[3] = (bf16)(v.w * sc);
    *(bf16x4*)(dst + idx) = o;
}

// ---------------- shared NT-GEMM core: C[m,n] = sum_k A[m,k]*B[n,k] ----------------
// 128x128 tile, BK=32, K=1024. 256 threads = 4 waves (2x2, each 64x64 = 4x4 MFMA tiles).
// BK=32 is the measured optimum (BK=64 regressed ~8us in R4 — m132 pattern).
__device__ __forceinline__ void gemm_core(const bf16* __restrict__ A, const bf16* __restrict__ B,
                                          int mBase, int nBase, bf16* As, bf16* Bs,
                                          f32x4 acc[4][4]) {
    const int tid = threadIdx.x;
    const int wave = tid >> 6, lane = tid & 63;
    const int g = lane >> 4, lr = lane & 15;
    const int wm = (wave & 1) << 6, wn = (wave >> 1) << 6;
    const int q = lane >> 2;
    const int cswz = ((lane & 3) ^ ((lane >> 3) & 3)) << 3;   // staging source chunk (elems)
    const int pcs  = (g ^ ((lr >> 1) & 3)) << 3;              // fragment physical chunk (elems)

    const int rb0 = wave << 4, rb1 = rb0 + 64;
    const bf16* a0 = A + (size_t)(mBase + rb0 + q) * 1024 + cswz;
    const bf16* a1 = A + (size_t)(mBase + rb1 + q) * 1024 + cswz;
    const bf16* b0 = B + (size_t)(nBase + rb0 + q) * 1024 + cswz;
    const bf16* b1 = B + (size_t)(nBase + rb1 + q) * 1024 + cswz;

    for (int k0 = 0; k0 < 1024; k0 += 32) {
        __syncthreads();
        gld_lds16(a0 + k0, As + rb0 * 32);
        gld_lds16(a1 + k0, As + rb1 * 32);
        gld_lds16(b0 + k0, Bs + rb0 * 32);
        gld_lds16(b1 + k0, Bs + rb1 * 32);
        __syncthreads();

        bf16x8 af[4], bfr[4];
#pragma unroll
        for (int i = 0; i < 4; i++)
            af[i] = *(const bf16x8*)&As[(wm + (i << 4) + lr) * 32 + pcs];
#pragma unroll
        for (int j = 0; j < 4; j++)
            bfr[j] = *(const bf16x8*)&Bs[(wn + (j << 4) + lr) * 32 + pcs];
#pragma unroll
        for (int i = 0; i < 4; i++)
#pragma unroll
            for (int j = 0; j < 4; j++)
                acc[i][j] = MFMA16(af[i], bfr[j], acc[i][j]);
    }
}

// ---------------- merged QKV GEMM, all epilogues coalesced ----------------
// Grid (32, 24). my<16: ROLE-SWAPPED Q/K — A = stacked [Wq;Wk] (contiguous in ws),
//   C[m=feature][n=token]; lane's r-axis = consecutive d -> bf16x4 (8B) stores to [b,h,t,d].
// my>=16: V natural — A = x, B = Wv, C[m=token][n=feature]; lane's r-axis = consecutive t
//   -> bf16x4 stores to V^T [b,h,d,t]. No scattered 2B stores anywhere.
__global__ __launch_bounds__(256) void gemm_qkv(const bf16* __restrict__ X,
                                                const bf16* __restrict__ Wqk,  // [2048][1024]
                                                const bf16* __restrict__ Wv,
                                                bf16* __restrict__ Qo, bf16* __restrict__ Ko,
                                                bf16* __restrict__ Vto) {
    __shared__ bf16 As[128 * 32];
    __shared__ bf16 Bs[128 * 32];
    const int tid = threadIdx.x;
    const int wave = tid >> 6, lane = tid & 63;
    const int g = lane >> 4, lr = lane & 15;
    const int wm = (wave & 1) << 6, wn = (wave >> 1) << 6;
    const int my = blockIdx.y;
    const bool qk = (my < 16);

    const bf16* Ap = qk ? Wqk : X;
    const bf16* Bp = qk ? X   : Wv;
    const int mBase = qk ? my * 128 : blockIdx.x * 128;
    const int nBase = qk ? blockIdx.x * 128 : (my - 16) * 128;

    f32x4 acc[4][4] = {};
    gemm_core(Ap, Bp, mBase, nBase, As, Bs, acc);

    // C/D layout: row m = g*4+r, col n = lr (verified m89/m91)
    if (qk) {
#pragma unroll
        for (int i = 0; i < 4; i++) {
            int m0 = mBase + wm + (i << 4) + (g << 2);   // feature row (stacked), +r along store
            bf16* dst = (m0 >> 10) ? Ko : Qo;
            int feat = m0 & 1023;
            int h = feat >> 6, d = feat & 63;
#pragma unroll
            for (int j = 0; j < 4; j++) {
                int t = nBase + wn + (j << 4) + lr;
                int b = t >> 11, tl = t & 2047;
                bf16x4 v;
#pragma unroll
                for (int r = 0; r < 4; r++) v[r] = (bf16)acc[i][j][r];
                *(bf16x4*)&dst[(((size_t)((b << 4) + h) * 2048 + tl) << 6) + d] = v;
            }
        }
    } else {
#pragma unroll
        for (int i = 0; i < 4; i++) {
            int t0 = mBase + wm + (i << 4) + (g << 2);   // token row, +r along store
            int b = t0 >> 11, tl = t0 & 2047;
#pragma unroll
            for (int j = 0; j < 4; j++) {
                int o = nBase + wn + (j << 4) + lr;
                int h = o >> 6, d = o & 63;
                bf16x4 v;
#pragma unroll
                for (int r = 0; r < 4; r++) v[r] = (bf16)acc[i][j][r];
                *(bf16x4*)&Vto[((size_t)(((b << 4) + h) << 6) + d) * 2048 + tl] = v;
            }
        }
    }
}

// ---------------- output GEMM (role-swapped): out = attn @ Wu^T + bu ----------------
// A = Wu (m=feature, 8 tiles), B = attnO (n=token, 32 tiles). Lane's r-axis = consecutive o
// -> float4 (16B) coalesced stores into out[t][o], bias via float4 load.
__global__ __launch_bounds__(256) void gemm_out(const bf16* __restrict__ Wu, const bf16* __restrict__ A,
                                                const float* __restrict__ bias, float* __restrict__ out) {
    __shared__ bf16 As[128 * 32];
    __shared__ bf16 Bs[128 * 32];
    const int tid = threadIdx.x;
    const int wave = tid >> 6, lane = tid & 63;
    const int g = lane >> 4, lr = lane & 15;
    const int wm = (wave & 1) << 6, wn = (wave >> 1) << 6;
    const int mBase = blockIdx.y * 128, nBase = blockIdx.x * 128;

    f32x4 acc[4][4] = {};
    gemm_core(Wu, A, mBase, nBase, As, Bs, acc);

#pragma unroll
    for (int i = 0; i < 4; i++) {
        int o = mBase + wm + (i << 4) + (g << 2);
        float4 bv = *(const float4*)&bias[o];
#pragma unroll
        for (int j = 0; j < 4; j++) {
            int t = nBase + wn + (j << 4) + lr;
            float4 v;
            v.x = acc[i][j][0] + bv.x;
            v.y = acc[i][j][1] + bv.y;
            v.z = acc[i][j][2] + bv.z;
            v.w = acc[i][j][3] + bv.w;
            *(float4*)&out[((size_t)t << 10) + o] = v;
        }
    }
}

// ---------------- attention ----------------
// Per block: one (b,h), 64 Q rows (4 waves x 16t). 1024 blocks, 40KB LDS -> ~4 blocks/CU.
// XCD-affinity: all 32 q-tiles of one bh share bid%8 -> per-XCD L2 holds 4 heads' K/V (2MB)
// (R5: FETCH_SIZE 70 -> 12MB, K/V served from L2).
// S^T = K@Q^T (C rows = s-dim); P via per-wave 1KB LDS plane; lsum via ones-MFMA
// (row-sums land with oacc's (g,r)->t mapping -> shuffle-free normalization).
// Wq pre-scaled by log2(e): exp is raw v_exp_f32.
__global__ __launch_bounds__(256, 4) void attn(const bf16* __restrict__ Q, const bf16* __restrict__ Kt,
                                               const bf16* __restrict__ Vt, bf16* __restrict__ O) {
    __shared__ bf16 Qs[2][64][32];    // 8KB [ks][t][d-half]; dead after qf extraction -> Ps alias
    __shared__ bf16 Ks[2][128][32];   // 16KB [ks][s][d-half]
    __shared__ bf16 Vs[4][64][32];    // 16KB [ks2][d][s-quarter]
    bf16 (*Ps)[16][32] = (bf16(*)[16][32]) & Qs[0][0][0];  // 4KB alias: [wave][t][s-quarter]

    const int tid = threadIdx.x;
    const int wave = tid >> 6, lane = tid & 63;
    const int g = lane >> 4, lr = lane & 15;
    const int q = lane >> 2;
    const int cswz = ((lane & 3) ^ ((lane >> 3) & 3)) << 3;
    const int pcs  = (g ^ ((lr >> 1) & 3)) << 3;
    // P-write physical offsets (b64): logical chunk isub*2+(g>>1), sub (g&1)*4, row lr
    const int pw0 = ((((g >> 1))     ^ ((lr >> 1) & 3)) << 3) + ((g & 1) << 2);
    const int pw1 = (((2 + (g >> 1)) ^ ((lr >> 1) & 3)) << 3) + ((g & 1) << 2);

    const int bid = blockIdx.x;
    const int bh = ((bid & 7) << 2) | (bid >> 8);   // 32 q-tiles of a bh share bid%8 (XCD hint)
    const int qt = (bid >> 3) & 31;
    const int qBase = qt << 6;

    const bf16* Qg = Q + ((size_t)bh * 2048 + qBase) * 64;
    const bf16* Kg = Kt + (size_t)bh * 2048 * 64;
    const bf16* Vg = Vt + (size_t)bh * 64 * 2048;

    // stage Q: 8 batches of 1KB, 2 per wave, plane-split [p][16 rows][32], swizzled source
#pragma unroll
    for (int i = 0; i < 2; i++) {
        int bi = (wave << 1) + i;
        int p = bi >> 2, rb = (bi & 3) << 4;
        gld_lds16(Qg + (rb + q) * 64 + (p << 5) + cswz, &Qs[p][rb][0]);
    }
    __syncthreads();

    bf16x8 qf[2];
#pragma unroll
    for (int ks = 0; ks < 2; ks++)
        qf[ks] = *(const bf16x8*)&Qs[ks][(wave << 4) + lr][pcs];

    bf16x8 ones;
#pragma unroll
    for (int i = 0; i < 8; i++) ones[i] = (bf16)1.0f;

    f32x4 oacc[4] = {};
    f32x4 oaccL = {};

    for (int s0 = 0; s0 < 2048; s0 += 128) {
        __syncthreads();   // drains lgkm: qf/prior-iter fragment reads done everywhere
#pragma unroll
        for (int i = 0; i < 4; i++) {
            int bi = (wave << 2) + i;
            {   // K chunk: [2][128][32]
                int p = bi >> 3, rb = (bi & 7) << 4;
                gld_lds16(Kg + (size_t)(s0 + rb + q) * 64 + (p << 5) + cswz, &Ks[p][rb][0]);
            }
            {   // V chunk: [4][64][32]
                int p = bi >> 2, rb = (bi & 3) << 4;
                gld_lds16(Vg + (size_t)(rb + q) * 2048 + s0 + (p << 5) + cswz, &Vs[p][rb][0]);
            }
        }
        __syncthreads();

#pragma unroll
        for (int ks2 = 0; ks2 < 4; ks2++) {
            // S^T for s-quarter ks2: tiles is = 2*ks2, 2*ks2+1
            f32x4 sacc[2] = {};
#pragma unroll
            for (int isub = 0; isub < 2; isub++) {
                int is = (ks2 << 1) + isub;
#pragma unroll
                for (int ks = 0; ks < 2; ks++) {
                    bf16x8 kf = *(const bf16x8*)&Ks[ks][(is << 4) + lr][pcs];
                    sacc[isub] = MFMA16(kf, qf[ks], sacc[isub]);
                }
            }
            // exp2 + pack into P plane [t=lr][32] (swizzled b64 writes)
#pragma unroll
            for (int isub = 0; isub < 2; isub++) {
                f32x4 s = sacc[isub];
                bf16x4 pb;
                pb[0] = (bf16)__builtin_amdgcn_exp2f(s[0]);
                pb[1] = (bf16)__builtin_amdgcn_exp2f(s[1]);
                pb[2] = (bf16)__builtin_amdgcn_exp2f(s[2]);
                pb[3] = (bf16)__builtin_amdgcn_exp2f(s[3]);
                *(bf16x4*)&Ps[wave][lr][isub ? pw1 : pw0] = pb;
            }
            // O += P @ V; L += P @ ones (same-wave DS in-order: no explicit waitcnt)
            bf16x8 pf = *(const bf16x8*)&Ps[wave][lr][pcs];
#pragma unroll
            for (int jd = 0; jd < 4; jd++) {
                bf16x8 vf = *(const bf16x8*)&Vs[ks2][(jd << 4) + lr][pcs];
                oacc[jd] = MFMA16(pf, vf, oacc[jd]);
            }
            oaccL = MFMA16(pf, ones, oaccL);
        }
    }

    // normalization: oaccL rows align with oacc rows (same A-fragment) -> no shuffles
    float linv[4];
#pragma unroll
    for (int r = 0; r < 4; r++) linv[r] = 1.0f / oaccL[r];

    const int b = bh >> 4, h = bh & 15;
#pragma unroll
    for (int jd = 0; jd < 4; jd++)
#pragma unroll
        for (int r = 0; r < 4; r++) {
            int t = qBase + (wave << 4) + (g << 2) + r;
            int col = (h << 6) + (jd << 4) + lr;
            O[(((size_t)(b * 2048 + t)) << 10) + col] = (bf16)(oacc[jd][r] * linv[r]);
        }
}

extern "C" void kernel_launch(void* const* d_in, const int* in_sizes, int n_in,
                              void* d_out, int out_size, void* d_ws, size_t ws_size,
                              hipStream_t stream) {
    const float* x  = (const float*)d_in[0];
    const float* Wq = (const float*)d_in[1];
    const float* Wk = (const float*)d_in[2];
    const float* Wv = (const float*)d_in[3];
    const float* Wu = (const float*)d_in[4];
    const float* bu = (const float*)d_in[5];
    float* out = (float*)d_out;

    char* ws = (char*)d_ws;
    bf16* xbf  = (bf16*)(ws);                      // 8MB; reused as attn output after QKV GEMM
    bf16* wqbf = (bf16*)(ws + ((size_t)8  << 20)); // wq+wk contiguous = stacked [2048][1024]
    bf16* wkbf = (bf16*)(ws + ((size_t)10 << 20));
    bf16* wvbf = (bf16*)(ws + ((size_t)12 << 20));
    bf16* wubf = (bf16*)(ws + ((size_t)14 << 20));
    bf16* Qb   = (bf16*)(ws + ((size_t)16 << 20)); // [b,h,t,d] 8MB
    bf16* Kb   = (bf16*)(ws + ((size_t)24 << 20)); // [b,h,t,d] 8MB
    bf16* Vtb  = (bf16*)(ws + ((size_t)32 << 20)); // [b,h,d,t] 8MB
    bf16* attnO = xbf;                             // overlay: x dead after gemm_qkv

    const float iscale_k = 0.17677669529663687f;   // 1024^-0.25
    const float iscale_q = 0.25503540109f;         // 1024^-0.25 * log2(e) -> scores in log2 domain

    cvt_all<<<8192, 256, 0, stream>>>(x, Wq, Wk, Wv, Wu, xbf, wqbf, wkbf, wvbf, wubf,
                                      iscale_q, iscale_k);

    gemm_qkv<<<dim3(32, 24), 256, 0, stream>>>(xbf, wqbf, wvbf, Qb, Kb, Vtb);
    attn<<<dim3(1024), 256, 0, stream>>>(Qb, Kb, Vtb, attnO);
    gemm_out<<<dim3(32, 8), 256, 0, stream>>>(wubf, attnO, bu, out);
}